// Round 1
// baseline (3148.669 us; speedup 1.0000x reference)
//
#include <hip/hip_runtime.h>
#include <math.h>

#define BB 4096
#define SS 128
#define HH 64
#define NB 8            // batch rows per block
#define NBLK (BB/NB)    // 512 blocks
#define NT 256

__device__ __forceinline__ float fsig(float x)  { return 1.f / (1.f + __expf(-x)); }
__device__ __forceinline__ float ftanh(float x) { return 1.f - 2.f / (__expf(2.f * x) + 1.f); }

__global__ __launch_bounds__(NT, 2)
void podcritic_fused(const float* __restrict__ self_obs,
                     const float* __restrict__ tm_obs,
                     const float* __restrict__ en_obs,
                     const float* __restrict__ cp_obs,
                     const float* __restrict__ W1, const float* __restrict__ b1,
                     const float* __restrict__ W2, const float* __restrict__ b2,
                     const float* __restrict__ Wih, const float* __restrict__ bih,
                     const float* __restrict__ Whh, const float* __restrict__ bhh,
                     const float* __restrict__ Wv, const float* __restrict__ bv,
                     float* __restrict__ out)
{
    __shared__ float sx[NB][48];      // x tile, padded 47->48 (pad col = 0)
    __shared__ float sh1[NB][256];
    __shared__ float semb[NB][128];
    __shared__ float sg[NB][256];     // gates
    __shared__ float sh[NB][64];
    __shared__ float sc[NB][64];
    __shared__ float sWv[64];

    const int t  = threadIdx.x;
    const int b0 = blockIdx.x * NB;

    // Persistent per-thread weight columns (reused across all 128 steps).
    float w1c[48];
    #pragma unroll
    for (int k = 0; k < 47; ++k) w1c[k] = W1[k * 256 + t];
    w1c[47] = 0.f;
    float whhc[64];
    #pragma unroll
    for (int k = 0; k < 64; ++k) whhc[k] = Whh[k * 256 + t];

    const float b1t = b1[t];
    const float b2t = b2[t & 127];
    const float bg  = bih[t] + bhh[t];   // fold the two gate biases
    const float bvv = bv[0];

    if (t < 64) sWv[t] = Wv[t];
    for (int idx = t; idx < NB * 64; idx += NT) {
        ((float*)sh)[idx] = 0.f;
        ((float*)sc)[idx] = 0.f;
    }
    __syncthreads();

    for (int s = 0; s < SS; ++s) {
        // ---- phase 1: gather + enemy-mean + concat -> x [NB][47] ----
        for (int idx = t; idx < NB * 48; idx += NT) {
            int r = idx / 48, k = idx - r * 48;
            int bs = (b0 + r) * SS + s;
            float v;
            if (k < 15)      v = self_obs[bs * 15 + k];
            else if (k < 28) v = tm_obs[bs * 13 + (k - 15)];
            else if (k < 41) { int kk = k - 28;
                               v = 0.5f * (en_obs[(bs * 2) * 13 + kk] + en_obs[(bs * 2 + 1) * 13 + kk]); }
            else if (k < 47) v = cp_obs[bs * 6 + (k - 41)];
            else             v = 0.f;
            sx[r][k] = v;
        }
        __syncthreads();

        // ---- phase 2: H1 = relu(x @ W1 + b1); thread t owns column t ----
        {
            float acc[NB];
            #pragma unroll
            for (int r = 0; r < NB; ++r) acc[r] = b1t;
            #pragma unroll
            for (int k4 = 0; k4 < 48; k4 += 4) {
                #pragma unroll
                for (int r = 0; r < NB; ++r) {
                    float4 xv = *(const float4*)&sx[r][k4];
                    acc[r] += xv.x * w1c[k4] + xv.y * w1c[k4 + 1]
                            + xv.z * w1c[k4 + 2] + xv.w * w1c[k4 + 3];
                }
            }
            #pragma unroll
            for (int r = 0; r < NB; ++r) sh1[r][t] = fmaxf(acc[r], 0.f);
        }
        __syncthreads();

        // ---- phase 3: EMB = relu(H1 @ W2 + b2); col = t&127, 4 rows each ----
        {
            const int col = t & 127;
            const int rb  = (t >> 7) * 4;
            float acc[4];
            #pragma unroll
            for (int r = 0; r < 4; ++r) acc[r] = b2t;
            for (int k4 = 0; k4 < 256; k4 += 4) {
                float w0 = W2[(k4 + 0) * 128 + col];
                float w1_ = W2[(k4 + 1) * 128 + col];
                float w2_ = W2[(k4 + 2) * 128 + col];
                float w3 = W2[(k4 + 3) * 128 + col];
                #pragma unroll
                for (int r = 0; r < 4; ++r) {
                    float4 hv = *(const float4*)&sh1[rb + r][k4];
                    acc[r] += hv.x * w0 + hv.y * w1_ + hv.z * w2_ + hv.w * w3;
                }
            }
            #pragma unroll
            for (int r = 0; r < 4; ++r) semb[rb + r][col] = fmaxf(acc[r], 0.f);
        }
        __syncthreads();

        // ---- phase 4: gates = emb @ Wih + h @ Whh + (bih+bhh); column t ----
        {
            float acc[NB];
            #pragma unroll
            for (int r = 0; r < NB; ++r) acc[r] = bg;
            for (int k4 = 0; k4 < 128; k4 += 4) {
                float w0 = Wih[(k4 + 0) * 256 + t];
                float w1_ = Wih[(k4 + 1) * 256 + t];
                float w2_ = Wih[(k4 + 2) * 256 + t];
                float w3 = Wih[(k4 + 3) * 256 + t];
                #pragma unroll
                for (int r = 0; r < NB; ++r) {
                    float4 ev = *(const float4*)&semb[r][k4];
                    acc[r] += ev.x * w0 + ev.y * w1_ + ev.z * w2_ + ev.w * w3;
                }
            }
            #pragma unroll
            for (int k4 = 0; k4 < 64; k4 += 4) {
                #pragma unroll
                for (int r = 0; r < NB; ++r) {
                    float4 hv = *(const float4*)&sh[r][k4];
                    acc[r] += hv.x * whhc[k4] + hv.y * whhc[k4 + 1]
                            + hv.z * whhc[k4 + 2] + hv.w * whhc[k4 + 3];
                }
            }
            #pragma unroll
            for (int r = 0; r < NB; ++r) sg[r][t] = acc[r];
        }
        __syncthreads();

        // ---- phase 5: pointwise LSTM cell update ----
        for (int idx = t; idx < NB * 64; idx += NT) {
            int r = idx >> 6, j = idx & 63;
            float gi = fsig(sg[r][j]);
            float gf = fsig(sg[r][64 + j]);
            float gg = ftanh(sg[r][128 + j]);
            float go = fsig(sg[r][192 + j]);
            float c  = gf * sc[r][j] + gi * gg;
            sc[r][j] = c;
            sh[r][j] = go * ftanh(c);
        }
        __syncthreads();

        // ---- phase 5b: val = h @ Wv + bv (wave w -> rows w and w+4) ----
        {
            int w = t >> 6, j = t & 63;
            #pragma unroll
            for (int rr = 0; rr < 2; ++rr) {
                int r = w + rr * 4;
                float p = sh[r][j] * sWv[j];
                #pragma unroll
                for (int off = 32; off > 0; off >>= 1) p += __shfl_down(p, off, 64);
                if (j == 0) out[(b0 + r) * SS + s] = p + bvv;
            }
        }
        __syncthreads();
    }

    // ---- epilogue: hn, cn ----
    for (int idx = t; idx < NB * 64; idx += NT) {
        int r = idx >> 6, j = idx & 63;
        out[BB * SS + (b0 + r) * 64 + j]            = sh[r][j];
        out[BB * SS + BB * 64 + (b0 + r) * 64 + j]  = sc[r][j];
    }
}

extern "C" void kernel_launch(void* const* d_in, const int* in_sizes, int n_in,
                              void* d_out, int out_size, void* d_ws, size_t ws_size,
                              hipStream_t stream) {
    const float* self_obs = (const float*)d_in[0];
    const float* tm_obs   = (const float*)d_in[1];
    const float* en_obs   = (const float*)d_in[2];
    const float* cp_obs   = (const float*)d_in[3];
    const float* W1  = (const float*)d_in[4];
    const float* b1  = (const float*)d_in[5];
    const float* W2  = (const float*)d_in[6];
    const float* b2  = (const float*)d_in[7];
    const float* Wih = (const float*)d_in[8];
    const float* bih = (const float*)d_in[9];
    const float* Whh = (const float*)d_in[10];
    const float* bhh = (const float*)d_in[11];
    const float* Wv  = (const float*)d_in[12];
    const float* bv  = (const float*)d_in[13];
    float* out = (float*)d_out;

    podcritic_fused<<<NBLK, NT, 0, stream>>>(
        self_obs, tm_obs, en_obs, cp_obs,
        W1, b1, W2, b2, Wih, bih, Whh, bhh, Wv, bv, out);
}

// Round 2
// 762.867 us; speedup vs baseline: 4.1274x; 4.1274x over previous
//
#include <hip/hip_runtime.h>

#define BB 4096
#define SS 128
#define NB 16
#define NBLK (BB/NB)    // 256 blocks
#define NT 256

typedef __attribute__((ext_vector_type(8))) short short8;
typedef __attribute__((ext_vector_type(4))) float f32x4;
typedef unsigned short ushort_t;

// LDS row strides (in bf16 elems): row stride = K + 8 pad -> 2-way (free) bank pattern
#define SX_STR   72     // x: K=64 (47 padded w/ zeros)
#define SH1_STR  264    // h1: K=256
#define SEMB_STR 136    // emb: K=128
#define SH_STR   72     // h: K=64

__device__ __forceinline__ ushort_t f2bf(float f) {
    union { float f; unsigned u; } x; x.f = f;
    unsigned r = x.u + 0x7FFFu + ((x.u >> 16) & 1u);   // RNE
    return (ushort_t)(r >> 16);
}
__device__ __forceinline__ float bf2f(ushort_t h) {
    union { unsigned u; float f; } x; x.u = ((unsigned)h) << 16; return x.f;
}
__device__ __forceinline__ float fsig(float x)  { return 1.f / (1.f + __expf(-x)); }
__device__ __forceinline__ float ftanh(float x) { return 1.f - 2.f / (__expf(2.f * x) + 1.f); }

union FragU { short8 v; ushort_t u[8]; };

__global__ __launch_bounds__(NT, 1)
void podcritic_mfma(const float* __restrict__ self_obs,
                    const float* __restrict__ tm_obs,
                    const float* __restrict__ en_obs,
                    const float* __restrict__ cp_obs,
                    const float* __restrict__ W1, const float* __restrict__ b1,
                    const float* __restrict__ W2, const float* __restrict__ b2,
                    const float* __restrict__ Wih, const float* __restrict__ bih,
                    const float* __restrict__ Whh, const float* __restrict__ bhh,
                    const float* __restrict__ Wv, const float* __restrict__ bv,
                    float* __restrict__ out)
{
    __shared__ __align__(16) ushort_t sx[2][NB * SX_STR];
    __shared__ __align__(16) ushort_t sh1[NB * SH1_STR];
    __shared__ __align__(16) ushort_t semb[NB * SEMB_STR];
    __shared__ __align__(16) ushort_t sh[NB * SH_STR];
    __shared__ float sWv[64];

    const int t  = threadIdx.x;
    const int w  = t >> 6;        // wave 0..3
    const int l  = t & 63;
    const int q  = l >> 4;        // quad 0..3
    const int m  = l & 15;        // row (A) / col (B,C) within tile
    const int b0 = blockIdx.x * NB;

    // ---------------- persistent weight B-fragments (bf16, VGPRs) ----------------
    // B-frag layout (16x16x32): lane holds col n = 16*tile + m, k = q*8 + j (+32*kk)
    short8 w1f[4][2];     // GEMM1: N-tiles {4w..4w+3}, K=64 (47 zero-padded)
    short8 w2f[2][8];     // GEMM2: N-tiles {2w,2w+1}, K=256
    short8 wihf[4][4];    // GEMM3: N-tiles {w, w+4, w+8, w+12}, K=128
    short8 whhf[4][2];    // GEMM4: same N-tiles, K=64
    float bias1[4], bias2[2], bg[4];

    #pragma unroll
    for (int i = 0; i < 4; ++i) {
        int n = w * 64 + i * 16 + m;
        bias1[i] = b1[n];
        #pragma unroll
        for (int kk = 0; kk < 2; ++kk) {
            FragU u;
            #pragma unroll
            for (int j = 0; j < 8; ++j) {
                int k = kk * 32 + q * 8 + j;
                u.u[j] = f2bf(k < 47 ? W1[k * 256 + n] : 0.f);
            }
            w1f[i][kk] = u.v;
        }
    }
    #pragma unroll
    for (int i = 0; i < 2; ++i) {
        int n = 32 * w + i * 16 + m;
        bias2[i] = b2[n];
        #pragma unroll
        for (int kk = 0; kk < 8; ++kk) {
            FragU u;
            #pragma unroll
            for (int j = 0; j < 8; ++j) {
                int k = kk * 32 + q * 8 + j;
                u.u[j] = f2bf(W2[k * 128 + n]);
            }
            w2f[i][kk] = u.v;
        }
    }
    #pragma unroll
    for (int i = 0; i < 4; ++i) {
        int n = (w + 4 * i) * 16 + m;      // gate columns: wave w owns hidden j in [16w,16w+16)
        bg[i] = bih[n] + bhh[n];
        #pragma unroll
        for (int kk = 0; kk < 4; ++kk) {
            FragU u;
            #pragma unroll
            for (int j = 0; j < 8; ++j) {
                int k = kk * 32 + q * 8 + j;
                u.u[j] = f2bf(Wih[k * 256 + n]);
            }
            wihf[i][kk] = u.v;
        }
        #pragma unroll
        for (int kk = 0; kk < 2; ++kk) {
            FragU u;
            #pragma unroll
            for (int j = 0; j < 8; ++j) {
                int k = kk * 32 + q * 8 + j;
                u.u[j] = f2bf(Whh[k * 256 + n]);
            }
            whhf[i][kk] = u.v;
        }
    }
    const float bvv = bv[0];
    if (t < 64) sWv[t] = Wv[t];

    // ---------------- init: h=0, x(s=0) gather ----------------
    for (int idx = t; idx < NB * SH_STR; idx += NT) sh[idx] = 0;

    const int pcol = t & 63;            // this thread's x column, fixed for the session
    const int prow = t >> 6;
    #pragma unroll
    for (int j = 0; j < 4; ++j) {
        int r  = 4 * j + prow;
        int bs = (b0 + r) * SS + 0;
        float v = 0.f;
        if (pcol < 15)      v = self_obs[bs * 15 + pcol];
        else if (pcol < 28) v = tm_obs[bs * 13 + (pcol - 15)];
        else if (pcol < 41) { int kk = pcol - 28;
                              v = 0.5f * (en_obs[(bs * 2) * 13 + kk] + en_obs[(bs * 2) * 13 + 13 + kk]); }
        else if (pcol < 47) v = cp_obs[bs * 6 + (pcol - 41)];
        sx[0][r * SX_STR + pcol] = f2bf(v);
    }
    __syncthreads();

    float creg[4] = {0.f, 0.f, 0.f, 0.f};
    float hreg[4] = {0.f, 0.f, 0.f, 0.f};
    int cur = 0;

    for (int s = 0; s < SS; ++s) {
        // ---- phase 0: prefetch x(s+1) to registers (latency hidden by GEMM1/2) ----
        float pf[4];
        #pragma unroll
        for (int j = 0; j < 4; ++j) {
            float v = 0.f;
            if (s + 1 < SS) {
                int r  = 4 * j + prow;
                int bs = (b0 + r) * SS + (s + 1);
                if (pcol < 15)      v = self_obs[bs * 15 + pcol];
                else if (pcol < 28) v = tm_obs[bs * 13 + (pcol - 15)];
                else if (pcol < 41) { int kk = pcol - 28;
                                      v = 0.5f * (en_obs[(bs * 2) * 13 + kk] + en_obs[(bs * 2) * 13 + 13 + kk]); }
                else if (pcol < 47) v = cp_obs[bs * 6 + (pcol - 41)];
            }
            pf[j] = v;
        }

        // ---- phase 1: H1 = relu(x @ W1 + b1)  [16 x 256] ----
        {
            f32x4 c1[4] = {{0,0,0,0},{0,0,0,0},{0,0,0,0},{0,0,0,0}};
            #pragma unroll
            for (int kk = 0; kk < 2; ++kk) {
                short8 a = *(const short8*)&sx[cur][m * SX_STR + kk * 32 + q * 8];
                #pragma unroll
                for (int i = 0; i < 4; ++i)
                    c1[i] = __builtin_amdgcn_mfma_f32_16x16x32_bf16(a, w1f[i][kk], c1[i], 0, 0, 0);
            }
            #pragma unroll
            for (int i = 0; i < 4; ++i) {
                int col = w * 64 + i * 16 + m;
                #pragma unroll
                for (int r = 0; r < 4; ++r) {
                    float v = fmaxf(c1[i][r] + bias1[i], 0.f);
                    sh1[(q * 4 + r) * SH1_STR + col] = f2bf(v);
                }
            }
        }
        __syncthreads();

        // ---- phase 2: EMB = relu(H1 @ W2 + b2)  [16 x 128] ----
        {
            f32x4 c2[2] = {{0,0,0,0},{0,0,0,0}};
            #pragma unroll
            for (int kk = 0; kk < 8; ++kk) {
                short8 a = *(const short8*)&sh1[m * SH1_STR + kk * 32 + q * 8];
                #pragma unroll
                for (int i = 0; i < 2; ++i)
                    c2[i] = __builtin_amdgcn_mfma_f32_16x16x32_bf16(a, w2f[i][kk], c2[i], 0, 0, 0);
            }
            #pragma unroll
            for (int i = 0; i < 2; ++i) {
                int col = 32 * w + i * 16 + m;
                #pragma unroll
                for (int r = 0; r < 4; ++r) {
                    float v = fmaxf(c2[i][r] + bias2[i], 0.f);
                    semb[(q * 4 + r) * SEMB_STR + col] = f2bf(v);
                }
            }
        }
        __syncthreads();

        // ---- phase 3: gates = emb@Wih + h@Whh + bg; pointwise LSTM in-reg ----
        {
            f32x4 g[4];
            #pragma unroll
            for (int i = 0; i < 4; ++i) g[i] = (f32x4){bg[i], bg[i], bg[i], bg[i]};
            #pragma unroll
            for (int kk = 0; kk < 4; ++kk) {
                short8 a = *(const short8*)&semb[m * SEMB_STR + kk * 32 + q * 8];
                #pragma unroll
                for (int i = 0; i < 4; ++i)
                    g[i] = __builtin_amdgcn_mfma_f32_16x16x32_bf16(a, wihf[i][kk], g[i], 0, 0, 0);
            }
            #pragma unroll
            for (int kk = 0; kk < 2; ++kk) {
                short8 a = *(const short8*)&sh[m * SH_STR + kk * 32 + q * 8];
                #pragma unroll
                for (int i = 0; i < 4; ++i)
                    g[i] = __builtin_amdgcn_mfma_f32_16x16x32_bf16(a, whhf[i][kk], g[i], 0, 0, 0);
            }
            // wave w holds i,f,g,o for hidden unit jcol = 16w+m, rows q*4+r
            const int jcol = 16 * w + m;
            #pragma unroll
            for (int r = 0; r < 4; ++r) {
                float gi = fsig(g[0][r]);
                float gf = fsig(g[1][r]);
                float gg = ftanh(g[2][r]);
                float go = fsig(g[3][r]);
                float c  = gf * creg[r] + gi * gg;
                creg[r] = c;
                float h = go * ftanh(c);
                hreg[r] = h;
                sh[(q * 4 + r) * SH_STR + jcol] = f2bf(h);
            }
            // store prefetched x(s+1)
            #pragma unroll
            for (int j = 0; j < 4; ++j) {
                int r = 4 * j + prow;
                sx[cur ^ 1][r * SX_STR + pcol] = f2bf(pf[j]);
            }
        }
        __syncthreads();

        // ---- phase 4: val = h @ Wv + bv ----
        {
            int r = t >> 4, p = t & 15;
            const ushort_t* hp = &sh[r * SH_STR + p * 4];
            float pv = 0.f;
            #pragma unroll
            for (int j = 0; j < 4; ++j) pv += bf2f(hp[j]) * sWv[p * 4 + j];
            pv += __shfl_xor(pv, 1, 16);
            pv += __shfl_xor(pv, 2, 16);
            pv += __shfl_xor(pv, 4, 16);
            pv += __shfl_xor(pv, 8, 16);
            if (p == 0) out[(b0 + r) * SS + s] = pv + bvv;
        }
        // no barrier needed: next write to sh happens after 2 more barriers
        cur ^= 1;
    }

    // ---- epilogue: hn, cn (fp32 from registers) ----
    {
        const int jcol = 16 * w + m;
        #pragma unroll
        for (int r = 0; r < 4; ++r) {
            int row = b0 + q * 4 + r;
            out[BB * SS + row * 64 + jcol]            = hreg[r];
            out[BB * SS + BB * 64 + row * 64 + jcol]  = creg[r];
        }
    }
}

extern "C" void kernel_launch(void* const* d_in, const int* in_sizes, int n_in,
                              void* d_out, int out_size, void* d_ws, size_t ws_size,
                              hipStream_t stream) {
    const float* self_obs = (const float*)d_in[0];
    const float* tm_obs   = (const float*)d_in[1];
    const float* en_obs   = (const float*)d_in[2];
    const float* cp_obs   = (const float*)d_in[3];
    const float* W1  = (const float*)d_in[4];
    const float* b1  = (const float*)d_in[5];
    const float* W2  = (const float*)d_in[6];
    const float* b2  = (const float*)d_in[7];
    const float* Wih = (const float*)d_in[8];
    const float* bih = (const float*)d_in[9];
    const float* Whh = (const float*)d_in[10];
    const float* bhh = (const float*)d_in[11];
    const float* Wv  = (const float*)d_in[12];
    const float* bv  = (const float*)d_in[13];
    float* out = (float*)d_out;

    podcritic_mfma<<<NBLK, NT, 0, stream>>>(
        self_obs, tm_obs, en_obs, cp_obs,
        W1, b1, W2, b2, Wih, bih, Whh, bhh, Wv, bv, out);
}